// Round 1
// baseline (2492.206 us; speedup 1.0000x reference)
//
#include <hip/hip_runtime.h>
#include <math.h>

#define S_LEN 2048
#define D_HEAD 64
#define TQ 16
#define NTHREADS 512
#define N_BH 32

// One block = one (b,h) x 16-query tile. Full score rows staged in LDS
// (16 x 2048 fp32 = 128 KB) so masked softmax + weights write + PV happen
// in a single sweep with no score recompute.
__global__ __launch_bounds__(NTHREADS, 1)
void sdpa_fp32_kernel(const float* __restrict__ Q, const float* __restrict__ K,
                      const float* __restrict__ V, const int* __restrict__ mask,
                      float* __restrict__ ctx, float* __restrict__ wout)
{
    __shared__ __align__(16) float s_lds[TQ][S_LEN];   // 128 KB scores -> weights -> scratch
    __shared__ __align__(16) float q_lds[TQ][D_HEAD];  // 4 KB

    const int t  = threadIdx.x;
    const int bh = blockIdx.y;
    const int q0 = blockIdx.x * TQ;

    const float* Qb = Q + ((size_t)bh * S_LEN + q0) * D_HEAD;
    const float* Kb = K + (size_t)bh * S_LEN * D_HEAD;
    const float* Vb = V + (size_t)bh * S_LEN * D_HEAD;
    const int*   Mb = mask + ((size_t)bh * S_LEN + q0) * (size_t)S_LEN;

    // stage Q tile
    for (int i = t; i < TQ * D_HEAD; i += NTHREADS)
        q_lds[i >> 6][i & 63] = Qb[i];
    __syncthreads();

    // ---- QK^T: one k-column per thread, 16 row-accumulators in registers ----
    for (int j = 0; j < S_LEN; j += NTHREADS) {
        const int k = j + t;
        float acc[TQ];
        #pragma unroll
        for (int r = 0; r < TQ; r++) acc[r] = 0.f;
        const float4* Krow = (const float4*)(Kb + (size_t)k * D_HEAD);
        #pragma unroll 4
        for (int d4 = 0; d4 < D_HEAD / 4; d4++) {
            const float4 kv = Krow[d4];
            #pragma unroll
            for (int r = 0; r < TQ; r++) {
                // uniform address across wave -> broadcast ds_read_b128
                const float4 qv = *(const float4*)&q_lds[r][d4 * 4];
                acc[r] += qv.x * kv.x + qv.y * kv.y + qv.z * kv.z + qv.w * kv.w;
            }
        }
        #pragma unroll
        for (int r = 0; r < TQ; r++) {
            const int mk = Mb[(size_t)r * S_LEN + k];   // coalesced int32 read
            s_lds[r][k] = mk ? -1e9f : acc[r] * 0.125f; // scale = 1/sqrt(64)
        }
    }
    __syncthreads();

    // ---- softmax: 32 threads per row (row fully inside one half-wave) ----
    {
        const int row = t >> 5;
        const int l32 = t & 31;
        float m = -INFINITY;
        for (int i = l32; i < S_LEN; i += 32) m = fmaxf(m, s_lds[row][i]);
        #pragma unroll
        for (int off = 16; off >= 1; off >>= 1) m = fmaxf(m, __shfl_xor(m, off));
        float sum = 0.f;
        for (int i = l32; i < S_LEN; i += 32) {
            const float e = __expf(s_lds[row][i] - m);
            s_lds[row][i] = e;
            sum += e;
        }
        #pragma unroll
        for (int off = 16; off >= 1; off >>= 1) sum += __shfl_xor(sum, off);
        const float inv = 1.f / sum;
        float* wrow = wout + ((size_t)bh * S_LEN + q0 + row) * (size_t)S_LEN;
        for (int i = l32; i < S_LEN; i += 32) {
            const float w = s_lds[row][i] * inv;
            s_lds[row][i] = w;      // keep normalized weights for PV
            wrow[i] = w;            // and emit output 1
        }
    }
    __syncthreads();

    // ---- PV: each wave owns a 256-wide k-stripe, partials for all 16 rows ----
    const int wv   = t >> 6;   // wave id 0..7
    const int lane = t & 63;   // = d
    float acc[TQ];
    #pragma unroll
    for (int r = 0; r < TQ; r++) acc[r] = 0.f;
    const int k_lo = wv * (S_LEN / 8), k_hi = k_lo + (S_LEN / 8);
    for (int k = k_lo; k < k_hi; k += 4) {
        const float v0 = Vb[(size_t)(k + 0) * D_HEAD + lane];  // coalesced
        const float v1 = Vb[(size_t)(k + 1) * D_HEAD + lane];
        const float v2 = Vb[(size_t)(k + 2) * D_HEAD + lane];
        const float v3 = Vb[(size_t)(k + 3) * D_HEAD + lane];
        #pragma unroll
        for (int r = 0; r < TQ; r++) {
            const float4 w4 = *(const float4*)&s_lds[r][k];    // broadcast b128
            acc[r] += w4.x * v0 + w4.y * v1 + w4.z * v2 + w4.w * v3;
        }
    }
    __syncthreads();                       // all waves done reading weights
    float* scratch = &s_lds[0][0];         // reuse: 8 x 16 x 64 fp32 = 32 KB
    #pragma unroll
    for (int r = 0; r < TQ; r++)
        scratch[((size_t)wv * TQ + r) * 64 + lane] = acc[r];
    __syncthreads();
    for (int o = t; o < TQ * D_HEAD; o += NTHREADS) {
        const int r = o >> 6, d = o & 63;
        float sum = 0.f;
        #pragma unroll
        for (int w = 0; w < 8; w++) sum += scratch[((size_t)w * TQ + r) * 64 + d];
        ctx[((size_t)bh * S_LEN + q0 + r) * D_HEAD + d] = sum;
    }
}

extern "C" void kernel_launch(void* const* d_in, const int* in_sizes, int n_in,
                              void* d_out, int out_size, void* d_ws, size_t ws_size,
                              hipStream_t stream) {
    const float* Q    = (const float*)d_in[0];
    const float* K    = (const float*)d_in[1];
    const float* V    = (const float*)d_in[2];
    const int*   mask = (const int*)d_in[3];

    float* ctx  = (float*)d_out;                                   // [2,16,2048,64]
    float* wout = (float*)d_out + (size_t)2 * 16 * 2048 * 64;      // [2,16,2048,2048]

    dim3 grid(S_LEN / TQ, N_BH);
    sdpa_fp32_kernel<<<grid, NTHREADS, 0, stream>>>(Q, K, V, mask, ctx, wout);
}

// Round 2
// 1154.793 us; speedup vs baseline: 2.1581x; 2.1581x over previous
//
#include <hip/hip_runtime.h>
#include <math.h>

#define S_LEN 2048
#define SPAD 2056          // bf16 elems per LDS score row: 16B-aligned stride, conflict-free
#define D_HEAD 64
#define TQ 16
#define NTHREADS 512
#define N_BH 32

typedef __attribute__((ext_vector_type(8))) short short8;   // 8 x bf16 (4 VGPRs) MFMA A/B frag
typedef __attribute__((ext_vector_type(4))) float float4v;  // MFMA C/D frag

__device__ inline short f2bf(float f) {               // fp32 -> bf16 bits, RNE
    union { float f; unsigned u; } x; x.f = f;
    unsigned r = x.u + 0x7FFFu + ((x.u >> 16) & 1u);
    return (short)(r >> 16);
}
__device__ inline float bf2f(short s) {
    union { unsigned u; float f; } x; x.u = ((unsigned)(unsigned short)s) << 16;
    return x.f;
}

// One block = one (b,h) x 16-query tile. QK^T and PV on bf16 MFMA; full score
// rows staged in LDS as bf16 (66 KB -> 2 blocks/CU). Wave w owns keys/k-range
// [w*256, w*256+256).
__global__ __launch_bounds__(NTHREADS, 4)
void sdpa_mfma_kernel(const float* __restrict__ Q, const float* __restrict__ K,
                      const float* __restrict__ V, const int* __restrict__ mask,
                      float* __restrict__ ctx, float* __restrict__ wout)
{
    __shared__ __align__(16) short s_bf[TQ * SPAD];    // scores -> weights (bf16), 65.8 KB
    __shared__ __align__(16) short q_bf[TQ * D_HEAD];  // Q tile bf16, 2 KB

    const int t    = threadIdx.x;
    const int bh   = blockIdx.y;
    const int q0   = blockIdx.x * TQ;
    const int wv   = t >> 6;       // wave 0..7
    const int lane = t & 63;
    const int m16  = lane & 15;    // free-dim index of A/B frags and C col
    const int g    = lane >> 4;    // k-group 0..3

    const float* Qb = Q + ((size_t)bh * S_LEN + q0) * D_HEAD;
    const float* Kb = K + (size_t)bh * S_LEN * D_HEAD;
    const float* Vb = V + (size_t)bh * S_LEN * D_HEAD;
    const int*   Mb = mask + ((size_t)bh * S_LEN + q0) * (size_t)S_LEN;

    // ---- stage Q tile as bf16 ----
    for (int i = t; i < TQ * D_HEAD; i += NTHREADS)
        q_bf[i] = f2bf(Qb[i]);
    __syncthreads();

    // A-frags for QK^T: a[j] = Q[m16][kc*32 + g*8 + j]  (16-B aligned LDS reads)
    const short8 a0 = *(const short8*)&q_bf[m16 * D_HEAD + 0  + g * 8];
    const short8 a1 = *(const short8*)&q_bf[m16 * D_HEAD + 32 + g * 8];

    // ---- QK^T: wave wv covers key cols [wv*256, wv*256+256), 16 tiles of 16 ----
    const int n_base = wv * 256;
    for (int nt = 0; nt < 16; nt++) {
        const int n0   = n_base + nt * 16;
        const int krow = n0 + m16;
        const float4v* kp = (const float4v*)(Kb + (size_t)krow * D_HEAD + g * 8);
        const float4v k0 = kp[0], k1 = kp[1];   // d = g*8..g*8+7
        const float4v k2 = kp[8], k3 = kp[9];   // d = 32+g*8..+7
        short8 b0, b1;
        #pragma unroll
        for (int j = 0; j < 4; j++) {
            b0[j] = f2bf(k0[j]); b0[4 + j] = f2bf(k1[j]);
            b1[j] = f2bf(k2[j]); b1[4 + j] = f2bf(k3[j]);
        }
        float4v acc = {0.f, 0.f, 0.f, 0.f};
        acc = __builtin_amdgcn_mfma_f32_16x16x32_bf16(a0, b0, acc, 0, 0, 0);
        acc = __builtin_amdgcn_mfma_f32_16x16x32_bf16(a1, b1, acc, 0, 0, 0);
        #pragma unroll
        for (int r = 0; r < 4; r++) {
            const int mrow = g * 4 + r;         // C row = query row
            const int mk = Mb[(size_t)mrow * S_LEN + n0 + m16];  // 4x64B lines/instr
            s_bf[mrow * SPAD + n0 + m16] = f2bf(mk ? -1e9f : acc[r] * 0.125f);
        }
    }
    __syncthreads();

    // ---- masked softmax: 32 threads per row, fp32 math on bf16-staged scores ----
    {
        const int row = t >> 5;
        const int l32 = t & 31;
        short* srow = &s_bf[row * SPAD];
        float m = -INFINITY;
        for (int i = l32; i < S_LEN; i += 32) m = fmaxf(m, bf2f(srow[i]));
        #pragma unroll
        for (int off = 16; off >= 1; off >>= 1) m = fmaxf(m, __shfl_xor(m, off));
        float sum = 0.f;
        for (int i = l32; i < S_LEN; i += 32) {
            const float e = __expf(bf2f(srow[i]) - m);
            srow[i] = f2bf(e);
            sum += e;
        }
        #pragma unroll
        for (int off = 16; off >= 1; off >>= 1) sum += __shfl_xor(sum, off);
        const float inv = 1.f / sum;
        float* wrow = wout + ((size_t)bh * S_LEN + q0 + row) * (size_t)S_LEN;
        for (int i = l32; i < S_LEN; i += 32) {
            const float w = bf2f(srow[i]) * inv;
            wrow[i] = w;            // output 1 (fp32)
            srow[i] = f2bf(w);      // normalized weights for PV
        }
    }
    __syncthreads();

    // ---- PV: wave wv owns k-range [wv*256, +256); 4 d-tiles of 16 ----
    float4v o[4] = {{0.f,0.f,0.f,0.f},{0.f,0.f,0.f,0.f},{0.f,0.f,0.f,0.f},{0.f,0.f,0.f,0.f}};
    const int k_base = wv * 256;
    for (int ks = 0; ks < 8; ks++) {
        const int k0 = k_base + ks * 32;
        // A-frag: P[m16][k0 + g*8 + j] — one 16-B LDS read, conflict-free
        const short8 af = *(const short8*)&s_bf[m16 * SPAD + k0 + g * 8];
        #pragma unroll
        for (int nt = 0; nt < 4; nt++) {
            const float* vp = Vb + (size_t)(k0 + g * 8) * D_HEAD + nt * 16 + m16;
            short8 bfv;
            #pragma unroll
            for (int j = 0; j < 8; j++) bfv[j] = f2bf(vp[(size_t)j * D_HEAD]); // 4x64B lines/instr
            o[nt] = __builtin_amdgcn_mfma_f32_16x16x32_bf16(af, bfv, o[nt], 0, 0, 0);
        }
    }
    __syncthreads();                      // all waves done reading weights from s_bf

    // ---- cross-wave reduce of PV partials through reused LDS (32 KB) ----
    float* scratch = (float*)s_bf;        // 8 waves x 16 x 64 fp32
    #pragma unroll
    for (int nt = 0; nt < 4; nt++)
        #pragma unroll
        for (int r = 0; r < 4; r++)
            scratch[wv * (TQ * D_HEAD) + (g * 4 + r) * D_HEAD + nt * 16 + m16] = o[nt][r];
    __syncthreads();
    for (int oi = t; oi < TQ * D_HEAD; oi += NTHREADS) {
        float sum = 0.f;
        #pragma unroll
        for (int w = 0; w < 8; w++) sum += scratch[w * (TQ * D_HEAD) + oi];
        ctx[((size_t)bh * S_LEN + q0) * D_HEAD + oi] = sum;
    }
}

extern "C" void kernel_launch(void* const* d_in, const int* in_sizes, int n_in,
                              void* d_out, int out_size, void* d_ws, size_t ws_size,
                              hipStream_t stream) {
    const float* Q    = (const float*)d_in[0];
    const float* K    = (const float*)d_in[1];
    const float* V    = (const float*)d_in[2];
    const int*   mask = (const int*)d_in[3];

    float* ctx  = (float*)d_out;                                   // [2,16,2048,64]
    float* wout = (float*)d_out + (size_t)2 * 16 * 2048 * 64;      // [2,16,2048,2048]

    dim3 grid(S_LEN / TQ, N_BH);
    sdpa_mfma_kernel<<<grid, NTHREADS, 0, stream>>>(Q, K, V, mask, ctx, wout);
}